// Round 19
// baseline (227.054 us; speedup 1.0000x reference)
//
#include <hip/hip_runtime.h>
#include <stdint.h>

#define B_ 4
#define T_ 2048
#define C_ 896
#define E_ 3
#define H_ 3584
#define N_ 8192
#define CVB 256   // dedicated W2-convert blocks prefixed to gemm1's grid
#define NRT 14    // ceil(capacity 3413 / 256)

typedef __attribute__((ext_vector_type(8))) short short8;
typedef __attribute__((ext_vector_type(4))) float f32x4;

// ---- ws layout (bytes) ----
#define OFF_XB   ((size_t)0)
#define OFF_W1B  ((size_t)14680064)
#define OFF_W2B  ((size_t)33947648)
#define OFF_HB   ((size_t)53215232)
#define OFF_PERM ((size_t)111935488)
#define OFF_EID  ((size_t)112033792)
#define OFF_GATE ((size_t)112066560)
#define OFF_PBUF ((size_t)112099328)
#define OFF_LSE2 ((size_t)112197632)
#define OFF_CNT  ((size_t)112230400)
#define OFF_P    OFF_XB   // N*C fp32 partial; xb/w1b dead after gemm1

static __device__ __forceinline__ unsigned short f2b(float f) {
  union { float f; unsigned u; } v; v.f = f;
  unsigned r = v.u + 0x7FFFu + ((v.u >> 16) & 1u);
  return (unsigned short)(r >> 16);
}

static __device__ __forceinline__ float gelu_fast(float v) {
  float u = 0.7978845608f * v * fmaf(0.044715f * v, v, 1.0f);
  u = fminf(u, 20.0f);
  float t = __expf(2.0f * u);
  return v * t * __builtin_amdgcn_rcpf(t + 1.0f);
}

static __device__ __forceinline__ int xcd_chunk(int lin, int total) {
  int q = total >> 3, r = total & 7;
  int xcd = lin & 7, idx = lin >> 3;
  return (xcd < r ? xcd * (q + 1) : r * (q + 1) + (xcd - r) * q) + idx;
}

static __device__ __forceinline__ void grp_decode(int t, int rt, int ncol, int RG, int CG,
                                                  int* rowt, int* colt) {
  const int fullbands = rt / RG;
  const int bandsz = RG * ncol;
  if (t < fullbands * bandsz) {
    int band = t / bandsz, tr = t % bandsz;
    int cg = tr / (CG * RG), r2 = tr % (CG * RG);
    *rowt = band * RG + r2 / CG;
    *colt = cg * CG + r2 % CG;
  } else {
    int t2 = t - fullbands * bandsz;
    int tail = rt - fullbands * RG;
    int cg = t2 / (CG * tail), r2 = t2 % (CG * tail);
    *rowt = fullbands * RG + r2 / CG;
    *colt = cg * CG + r2 % CG;
  }
}

static __device__ __forceinline__ void cvt_stride(const float* __restrict__ src,
                                                  unsigned short* __restrict__ dst,
                                                  int n4, int bid, int nblk) {
  const int stride = nblk * blockDim.x;
  for (int i = bid * blockDim.x + threadIdx.x; i < n4; i += stride) {
    float4 v = reinterpret_cast<const float4*>(src)[i];
    ushort4 o;
    o.x = f2b(v.x); o.y = f2b(v.y); o.z = f2b(v.z); o.w = f2b(v.w);
    reinterpret_cast<ushort4*>(dst)[i] = o;
  }
}

// ---- router (+fused W1 convert) ----
__global__ __launch_bounds__(256) void router_kernel(
    const float* __restrict__ x, const float* __restrict__ Wr,
    unsigned short* __restrict__ xb,
    int* __restrict__ eid, float* __restrict__ gate,
    float* __restrict__ pbuf, float* __restrict__ lse2,
    const float* __restrict__ W1, unsigned short* __restrict__ w1b) {
  if (blockIdx.x >= N_ / 8) {
    cvt_stride(W1, w1b, E_ * H_ * C_ / 4, blockIdx.x - N_ / 8, 1024);
    return;
  }
  const int tid = threadIdx.x;
  const int sub = tid & 31;
  const int n = blockIdx.x * 8 + (tid >> 5);
  const float4* xr = reinterpret_cast<const float4*>(x + (size_t)n * C_);
  ushort4* xw = reinterpret_cast<ushort4*>(xb + (size_t)n * C_);
  const float4* w0p = reinterpret_cast<const float4*>(Wr + 0 * C_);
  const float4* w1p = reinterpret_cast<const float4*>(Wr + 1 * C_);
  const float4* w2p = reinterpret_cast<const float4*>(Wr + 2 * C_);
  float s0 = 0.f, s1 = 0.f, s2 = 0.f;
#pragma unroll
  for (int j = 0; j < 7; ++j) {
    const int idx = sub + 32 * j;
    float4 v = xr[idx];
    ushort4 o;
    o.x = f2b(v.x); o.y = f2b(v.y); o.z = f2b(v.z); o.w = f2b(v.w);
    xw[idx] = o;
    float4 a = w0p[idx], b = w1p[idx], c = w2p[idx];
    s0 += v.x * a.x + v.y * a.y + v.z * a.z + v.w * a.w;
    s1 += v.x * b.x + v.y * b.y + v.z * b.z + v.w * b.w;
    s2 += v.x * c.x + v.y * c.y + v.z * c.z + v.w * c.w;
  }
#pragma unroll
  for (int off = 16; off > 0; off >>= 1) {
    s0 += __shfl_xor(s0, off);
    s1 += __shfl_xor(s1, off);
    s2 += __shfl_xor(s2, off);
  }
  if (sub == 0) {
    float m = fmaxf(s0, fmaxf(s1, s2));
    float e0 = expf(s0 - m), e1 = expf(s1 - m), e2 = expf(s2 - m);
    float sum = e0 + e1 + e2;
    float p0 = e0 / sum, p1 = e1 / sum, p2 = e2 / sum;
    int am = 0; float best = s0;
    if (s1 > best) { best = s1; am = 1; }
    if (s2 > best) { best = s2; am = 2; }
    float pa = (am == 0) ? p0 : ((am == 1) ? p1 : p2);
    eid[n] = am;
    gate[n] = pa / (pa + 1e-6f);
    pbuf[n * 3 + 0] = p0; pbuf[n * 3 + 1] = p1; pbuf[n * 3 + 2] = p2;
    float lse = m + logf(sum);
    lse2[n] = lse * lse;
  }
}

// ---- scatter: block-aggregated ----
__global__ __launch_bounds__(1024) void scatter_kernel(const int* __restrict__ eid,
                                                       int* __restrict__ counts,
                                                       int* __restrict__ perm) {
  __shared__ int hist[E_];
  __shared__ int base[E_];
  const int t = threadIdx.x;
  const int n = blockIdx.x * 1024 + t;
  if (t < E_) hist[t] = 0;
  __syncthreads();
  int e = eid[n];
  int l = atomicAdd(&hist[e], 1);
  __syncthreads();
  if (t < E_) base[t] = atomicAdd(&counts[t], hist[t]);
  __syncthreads();
  perm[e * N_ + base[e] + l] = n;
}

// ======== GEMM1: 256x128 tile, BK=32 DOUBLE-BUFFER, counted vmcnt(3) pipeline ========
// dbuf fits 48KB (2 x (16K A + 8K B)) -> occupancy UNCHANGED vs R16 single-buffer.
// Swizzle (64B rows, 4 slots): source slot (lane&3)^((lane>>2)&3); read slot
// (lane>>4)^(lane&3). LDS[row][d] = logical[d ^ (row&3)], involution verified.
#define STAGE1D(bufA, bufB)                                                             \
  do {                                                                                  \
    _Pragma("unroll")                                                                   \
    for (int i_ = 0; i_ < 2; ++i_) {                                                    \
      __builtin_amdgcn_global_load_lds(                                                 \
          (const __attribute__((address_space(1))) void*)pA_[i_],                       \
          (__attribute__((address_space(3))) void*)&(bufA)[(wv * 32 + i_ * 16) * 32], 16, 0, 0); \
    }                                                                                   \
    __builtin_amdgcn_global_load_lds(                                                   \
        (const __attribute__((address_space(1))) void*)pB_[0],                          \
        (__attribute__((address_space(3))) void*)&(bufB)[(wv * 16) * 32], 16, 0, 0);    \
    pA_[0] += 32; pA_[1] += 32; pB_[0] += 32;                                           \
  } while (0)

#define COMPUTE1D(bufA, bufB)                                                           \
  do {                                                                                  \
    const int sl_ = (((lane >> 4) ^ (lane & 3))) * 8;                                   \
    short8 af[4], bfv[4];                                                               \
    _Pragma("unroll")                                                                   \
    for (int m = 0; m < 4; ++m) {                                                       \
      int row = wm * 64 + m * 16 + (lane & 15);                                         \
      af[m] = *reinterpret_cast<const short8*>(&(bufA)[row * 32 + sl_]);                \
    }                                                                                   \
    _Pragma("unroll")                                                                   \
    for (int nn = 0; nn < 4; ++nn) {                                                    \
      int row = wn * 64 + nn * 16 + (lane & 15);                                        \
      bfv[nn] = *reinterpret_cast<const short8*>(&(bufB)[row * 32 + sl_]);              \
    }                                                                                   \
    _Pragma("unroll")                                                                   \
    for (int m = 0; m < 4; ++m)                                                         \
      _Pragma("unroll")                                                                 \
      for (int nn = 0; nn < 4; ++nn)                                                    \
        acc[m][nn] = __builtin_amdgcn_mfma_f32_16x16x32_bf16(af[m], bfv[nn], acc[m][nn], 0, 0, 0); \
  } while (0)

__global__ __launch_bounds__(512) void gemm1_kernel(
    const unsigned short* __restrict__ xb,
    const unsigned short* __restrict__ w1b,
    unsigned short* __restrict__ h,
    const int* __restrict__ perm, const int* __restrict__ counts,
    const float* __restrict__ W2, unsigned short* __restrict__ w2b) {
  if (blockIdx.x < CVB) {
    cvt_stride(W2, w2b, E_ * C_ * H_ / 4, blockIdx.x, CVB);
    return;
  }
  const int c0 = counts[0], c1 = counts[1], c2 = counts[2];
  const int rt0 = (c0 + 255) >> 8, rt1 = (c1 + 255) >> 8, rt2 = (c2 + 255) >> 8;
  const int n0 = rt0 * 28, n1 = rt1 * 28, n2 = rt2 * 28;
  const int total = n0 + n1 + n2;
  const int lin = blockIdx.x - CVB;
  if (lin >= total) return;
  const int wgid = xcd_chunk(lin, total);
  int e, rem, rt_e, count;
  if (wgid < n0)            { e = 0; rem = wgid;           rt_e = rt0; count = c0; }
  else if (wgid < n0 + n1)  { e = 1; rem = wgid - n0;      rt_e = rt1; count = c1; }
  else                      { e = 2; rem = wgid - n0 - n1; rt_e = rt2; count = c2; }
  int rowt, colt;
  grp_decode(rem, rt_e, 28, 4, 7, &rowt, &colt);   // 3.4 MB working set < 4 MiB L2
  const int row0 = rowt * 256;
  const int col0 = colt * 128;
  const int tid = threadIdx.x, lane = tid & 63, wv = tid >> 6;
  const int wm = wv >> 1, wn = wv & 1;
  const int* permE = perm + e * N_;
  const unsigned short* w1e = w1b + (size_t)e * H_ * C_;

  __shared__ __align__(16) unsigned short shA[2][256 * 32];
  __shared__ __align__(16) unsigned short shB[2][128 * 32];

  f32x4 acc[4][4];
#pragma unroll
  for (int i = 0; i < 4; ++i)
#pragma unroll
    for (int j = 0; j < 4; ++j) acc[i][j] = (f32x4){0.f, 0.f, 0.f, 0.f};

  const int cc2 = (((lane & 3) ^ ((lane >> 2) & 3))) * 8;   // pre-swizzled source slot
  const unsigned short* pA_[2];
  const unsigned short* pB_[1];
#pragma unroll
  for (int i = 0; i < 2; ++i) {
    int s = row0 + wv * 32 + i * 16 + (lane >> 2);
    if (s >= count) s = count - 1;
    pA_[i] = xb + (size_t)permE[s] * C_ + cc2;
  }
  {
    int r = wv * 16 + (lane >> 2);
    pB_[0] = w1e + (size_t)(col0 + r) * C_ + cc2;
  }

  const int NT = C_ / 32;   // 28 K-steps
  STAGE1D(shA[0], shB[0]);
  int cur = 0;
  for (int kt = 0; kt < NT; ++kt) {
    if (kt + 1 < NT) {
      if (cur) { STAGE1D(shA[0], shB[0]); } else { STAGE1D(shA[1], shB[1]); }
      asm volatile("s_waitcnt vmcnt(3)" ::: "memory");
    } else {
      asm volatile("s_waitcnt vmcnt(0)" ::: "memory");
    }
    __builtin_amdgcn_s_barrier();
    if (cur) { COMPUTE1D(shA[1], shB[1]); } else { COMPUTE1D(shA[0], shB[0]); }
    asm volatile("" ::: "memory");
    __builtin_amdgcn_s_barrier();
    cur ^= 1;
  }

#pragma unroll
  for (int m = 0; m < 4; ++m) {
    int rbase = wm * 64 + m * 16 + (lane >> 4) * 4;
#pragma unroll
    for (int i = 0; i < 4; ++i) {
      int s = row0 + rbase + i;
      if (s < count) {
        int ntok = permE[s];
#pragma unroll
        for (int nn = 0; nn < 4; ++nn) {
          int col = col0 + wn * 64 + nn * 16 + (lane & 15);
          h[(size_t)ntok * H_ + col] = f2b(gelu_fast(acc[m][nn][i]));
        }
      }
    }
  }
}

// ======== GEMM2: R16-exact — 256x128, BK=64 single-buffer, split-K x2 + P ========
#define STAGE2()                                                                        \
  do {                                                                                  \
    _Pragma("unroll")                                                                   \
    for (int i_ = 0; i_ < 4; ++i_) {                                                    \
      __builtin_amdgcn_global_load_lds(                                                 \
          (const __attribute__((address_space(1))) void*)pA_[i_],                       \
          (__attribute__((address_space(3))) void*)&shA[(wv * 4 + i_) * 512], 16, 0, 0); \
    }                                                                                   \
    _Pragma("unroll")                                                                   \
    for (int i_ = 0; i_ < 2; ++i_) {                                                    \
      __builtin_amdgcn_global_load_lds(                                                 \
          (const __attribute__((address_space(1))) void*)pB_[i_],                       \
          (__attribute__((address_space(3))) void*)&shB[(wv * 2 + i_) * 512], 16, 0, 0); \
    }                                                                                   \
    _Pragma("unroll")                                                                   \
    for (int i_ = 0; i_ < 4; ++i_) { pA_[i_] += 64; }                                   \
    _Pragma("unroll")                                                                   \
    for (int i_ = 0; i_ < 2; ++i_) { pB_[i_] += 64; }                                   \
  } while (0)

#define COMPUTE2()                                                                      \
  do {                                                                                  \
    _Pragma("unroll")                                                                   \
    for (int kk = 0; kk < 2; ++kk) {                                                    \
      const int sl_ = ((kk * 4 + (lane >> 4)) ^ (lane & 7)) * 8;                        \
      short8 af[4], bfv[4];                                                             \
      _Pragma("unroll")                                                                 \
      for (int m = 0; m < 4; ++m) {                                                     \
        int row = wm * 64 + m * 16 + (lane & 15);                                       \
        af[m] = *reinterpret_cast<const short8*>(&shA[row * 64 + sl_]);                 \
      }                                                                                 \
      _Pragma("unroll")                                                                 \
      for (int nn = 0; nn < 4; ++nn) {                                                  \
        int row = wn * 64 + nn * 16 + (lane & 15);                                      \
        bfv[nn] = *reinterpret_cast<const short8*>(&shB[row * 64 + sl_]);               \
      }                                                                                 \
      _Pragma("unroll")                                                                 \
      for (int m = 0; m < 4; ++m)                                                       \
        _Pragma("unroll")                                                               \
        for (int nn = 0; nn < 4; ++nn)                                                  \
          acc[m][nn] = __builtin_amdgcn_mfma_f32_16x16x32_bf16(af[m], bfv[nn], acc[m][nn], 0, 0, 0); \
    }                                                                                   \
  } while (0)

__global__ __launch_bounds__(512) void gemm2_kernel(
    const unsigned short* __restrict__ h,
    const unsigned short* __restrict__ w2b,
    const float* __restrict__ x,
    const float* __restrict__ gate,
    float* __restrict__ out, float* __restrict__ P,
    const int* __restrict__ perm, const int* __restrict__ counts) {
  const int c0 = counts[0], c1 = counts[1], c2 = counts[2];
  const int rt0 = (c0 + 255) >> 8, rt1 = (c1 + 255) >> 8, rt2 = (c2 + 255) >> 8;
  const int n0 = rt0 * 14, n1 = rt1 * 14, n2 = rt2 * 14;
  const int total = n0 + n1 + n2;
  const int lin = blockIdx.x;
  if (lin >= total) return;
  const int wgid = xcd_chunk(lin, total);
  int e, rem, rt_e, count;
  if (wgid < n0)            { e = 0; rem = wgid;           rt_e = rt0; count = c0; }
  else if (wgid < n0 + n1)  { e = 1; rem = wgid - n0;      rt_e = rt1; count = c1; }
  else                      { e = 2; rem = wgid - n0 - n1; rt_e = rt2; count = c2; }
  int rowt, c14;
  grp_decode(rem, rt_e, 14, 2, 7, &rowt, &c14);
  const int ks = c14 / 7;
  const int colt = c14 % 7;
  const int row0 = rowt * 256;
  const int col0 = colt * 128;
  const int kbase = ks * (H_ / 2);
  const int tid = threadIdx.x, lane = tid & 63, wv = tid >> 6;
  const int wm = wv >> 1, wn = wv & 1;
  const int* permE = perm + e * N_;
  const unsigned short* w2e = w2b + (size_t)e * C_ * H_;

  __shared__ __align__(16) unsigned short shA[256 * 64];
  __shared__ __align__(16) unsigned short shB[128 * 64];

  f32x4 acc[4][4];
#pragma unroll
  for (int i = 0; i < 4; ++i)
#pragma unroll
    for (int j = 0; j < 4; ++j) acc[i][j] = (f32x4){0.f, 0.f, 0.f, 0.f};

  const int cc = (((lane & 7) ^ (lane >> 3))) * 8;
  const unsigned short* pA_[4];
  const unsigned short* pB_[2];
#pragma unroll
  for (int i = 0; i < 4; ++i) {
    int s = row0 + wv * 32 + i * 8 + (lane >> 3);
    if (s >= count) s = count - 1;
    pA_[i] = h + (size_t)permE[s] * H_ + kbase + cc;
  }
#pragma unroll
  for (int i = 0; i < 2; ++i) {
    int r = wv * 16 + i * 8 + (lane >> 3);
    pB_[i] = w2e + (size_t)(col0 + r) * H_ + kbase + cc;
  }

  for (int kt = 0; kt < (H_ / 2) / 64; ++kt) {   // 28 K-steps
    STAGE2();
    __syncthreads();
    COMPUTE2();
    __syncthreads();
  }

#pragma unroll
  for (int m = 0; m < 4; ++m) {
    int rbase = wm * 64 + m * 16 + (lane >> 4) * 4;
#pragma unroll
    for (int i = 0; i < 4; ++i) {
      int s = row0 + rbase + i;
      if (s < count) {
        int ntok = permE[s];
        float g = gate[ntok];
        if (ks == 0) {
#pragma unroll
          for (int nn = 0; nn < 4; ++nn) {
            int col = col0 + wn * 64 + nn * 16 + (lane & 15);
            out[(size_t)ntok * C_ + col] = x[(size_t)ntok * C_ + col] + g * acc[m][nn][i];
          }
        } else {
#pragma unroll
          for (int nn = 0; nn < 4; ++nn) {
            int col = col0 + wn * 64 + nn * 16 + (lane & 15);
            P[(size_t)ntok * C_ + col] = g * acc[m][nn][i];
          }
        }
      }
    }
  }
}

// ---- combine: out += P; block 0 additionally computes the losses ----
__global__ __launch_bounds__(256) void combine_kernel(
    float* __restrict__ out, const float* __restrict__ P, int n4,
    const float* __restrict__ lse2, const float* __restrict__ pbuf,
    const int* __restrict__ eid) {
  int stride = gridDim.x * blockDim.x;
  for (int i = blockIdx.x * blockDim.x + threadIdx.x; i < n4; i += stride) {
    float4 a = reinterpret_cast<float4*>(out)[i];
    float4 b = reinterpret_cast<const float4*>(P)[i];
    a.x += b.x; a.y += b.y; a.z += b.z; a.w += b.w;
    reinterpret_cast<float4*>(out)[i] = a;
  }
  if (blockIdx.x == 0) {
    __shared__ float sh[7][256];
    float a = 0.f, p0 = 0.f, p1 = 0.f, p2 = 0.f, c0 = 0.f, c1 = 0.f, c2 = 0.f;
    for (int n = threadIdx.x; n < N_; n += 256) {
      a += lse2[n];
      p0 += pbuf[n * 3 + 0]; p1 += pbuf[n * 3 + 1]; p2 += pbuf[n * 3 + 2];
      int e = eid[n];
      c0 += (e == 0); c1 += (e == 1); c2 += (e == 2);
    }
    sh[0][threadIdx.x] = a;
    sh[1][threadIdx.x] = p0; sh[2][threadIdx.x] = p1; sh[3][threadIdx.x] = p2;
    sh[4][threadIdx.x] = c0; sh[5][threadIdx.x] = c1; sh[6][threadIdx.x] = c2;
    for (int s = 128; s > 0; s >>= 1) {
      __syncthreads();
      if (threadIdx.x < (unsigned)s)
#pragma unroll
        for (int q = 0; q < 7; ++q) sh[q][threadIdx.x] += sh[q][threadIdx.x + s];
    }
    if (threadIdx.x == 0) {
      const float invN = 1.0f / (float)N_;
      float z = 0.001f * (sh[0][0] * invN);
      float aux = 0.1f * (float)E_ *
                  (sh[4][0] * invN * sh[1][0] * invN +
                   sh[5][0] * invN * sh[2][0] * invN +
                   sh[6][0] * invN * sh[3][0] * invN);
      out[(size_t)N_ * C_] = z + aux;
    }
  }
}

extern "C" void kernel_launch(void* const* d_in, const int* in_sizes, int n_in,
                              void* d_out, int out_size, void* d_ws, size_t ws_size,
                              hipStream_t stream) {
  const float* x  = (const float*)d_in[0];
  const float* Wr = (const float*)d_in[1];
  const float* W1 = (const float*)d_in[2];
  const float* W2 = (const float*)d_in[3];
  float* out = (float*)d_out;
  char* ws = (char*)d_ws;

  unsigned short* xb  = (unsigned short*)(ws + OFF_XB);
  unsigned short* w1b = (unsigned short*)(ws + OFF_W1B);
  unsigned short* w2b = (unsigned short*)(ws + OFF_W2B);
  unsigned short* hb  = (unsigned short*)(ws + OFF_HB);
  int*   perm  = (int*)(ws + OFF_PERM);
  int*   eid   = (int*)(ws + OFF_EID);
  float* gate  = (float*)(ws + OFF_GATE);
  float* pbuf  = (float*)(ws + OFF_PBUF);
  float* lse2  = (float*)(ws + OFF_LSE2);
  int*   counts = (int*)(ws + OFF_CNT);
  float* P     = (float*)(ws + OFF_P);

  hipMemsetAsync(counts, 0, E_ * sizeof(int), stream);

  // router blocks [0,1024) + W1-convert blocks [1024,2048)
  router_kernel<<<2048, 256, 0, stream>>>(x, Wr, xb, eid, gate, pbuf, lse2, W1, w1b);
  scatter_kernel<<<N_ / 1024, 1024, 0, stream>>>(eid, counts, perm);

  // W2-convert blocks [0,CVB) + gemm1 blocks [CVB, CVB + 14*28*3)
  gemm1_kernel<<<CVB + NRT * 28 * E_, 512, 0, stream>>>(xb, w1b, hb, perm, counts, W2, w2b);
  gemm2_kernel<<<NRT * 14 * E_, 512, 0, stream>>>(hb, w2b, x, gate, out, P, perm, counts);
  combine_kernel<<<2048, 256, 0, stream>>>(out, P, N_ * C_ / 4, lse2, pbuf, eid);
}

// Round 22
// 177.308 us; speedup vs baseline: 1.2806x; 1.2806x over previous
//
#include <hip/hip_runtime.h>
#include <stdint.h>

#define B_ 4
#define T_ 2048
#define C_ 896
#define E_ 3
#define H_ 3584
#define N_ 8192
#define CVB 256   // dedicated W2-convert blocks prefixed to gemm1's grid
#define NRT 14    // ceil(capacity 3413 / 256)

typedef __attribute__((ext_vector_type(8))) short short8;
typedef __attribute__((ext_vector_type(4))) float f32x4;

// ---- ws layout (bytes) ----
#define OFF_XB   ((size_t)0)
#define OFF_W1B  ((size_t)14680064)
#define OFF_W2B  ((size_t)33947648)
#define OFF_HB   ((size_t)53215232)   // N*H bf16, COMPACT rows; base_e = prefix(counts)
#define OFF_PERM ((size_t)111935488)
#define OFF_EID  ((size_t)112033792)
#define OFF_GATE ((size_t)112066560)
#define OFF_PBUF ((size_t)112099328)
#define OFF_LSE2 ((size_t)112197632)
#define OFF_CNT  ((size_t)112230400)
#define OFF_P    OFF_XB   // N*C fp32 partial; xb/w1b dead after gemm1

static __device__ __forceinline__ unsigned short f2b(float f) {
  union { float f; unsigned u; } v; v.f = f;
  unsigned r = v.u + 0x7FFFu + ((v.u >> 16) & 1u);
  return (unsigned short)(r >> 16);
}

static __device__ __forceinline__ float gelu_fast(float v) {
  float u = 0.7978845608f * v * fmaf(0.044715f * v, v, 1.0f);
  u = fminf(u, 20.0f);
  float t = __expf(2.0f * u);
  return v * t * __builtin_amdgcn_rcpf(t + 1.0f);
}

static __device__ __forceinline__ int xcd_chunk(int lin, int total) {
  int q = total >> 3, r = total & 7;
  int xcd = lin & 7, idx = lin >> 3;
  return (xcd < r ? xcd * (q + 1) : r * (q + 1) + (xcd - r) * q) + idx;
}

static __device__ __forceinline__ void grp_decode(int t, int rt, int ncol, int RG, int CG,
                                                  int* rowt, int* colt) {
  const int fullbands = rt / RG;
  const int bandsz = RG * ncol;
  if (t < fullbands * bandsz) {
    int band = t / bandsz, tr = t % bandsz;
    int cg = tr / (CG * RG), r2 = tr % (CG * RG);
    *rowt = band * RG + r2 / CG;
    *colt = cg * CG + r2 % CG;
  } else {
    int t2 = t - fullbands * bandsz;
    int tail = rt - fullbands * RG;
    int cg = t2 / (CG * tail), r2 = t2 % (CG * tail);
    *rowt = fullbands * RG + r2 / CG;
    *colt = cg * CG + r2 % CG;
  }
}

static __device__ __forceinline__ void cvt_stride(const float* __restrict__ src,
                                                  unsigned short* __restrict__ dst,
                                                  int n4, int bid, int nblk) {
  const int stride = nblk * blockDim.x;
  for (int i = bid * blockDim.x + threadIdx.x; i < n4; i += stride) {
    float4 v = reinterpret_cast<const float4*>(src)[i];
    ushort4 o;
    o.x = f2b(v.x); o.y = f2b(v.y); o.z = f2b(v.z); o.w = f2b(v.w);
    reinterpret_cast<ushort4*>(dst)[i] = o;
  }
}

// ---- router (+fused W1 convert) ----
__global__ __launch_bounds__(256) void router_kernel(
    const float* __restrict__ x, const float* __restrict__ Wr,
    unsigned short* __restrict__ xb,
    int* __restrict__ eid, float* __restrict__ gate,
    float* __restrict__ pbuf, float* __restrict__ lse2,
    const float* __restrict__ W1, unsigned short* __restrict__ w1b) {
  if (blockIdx.x >= N_ / 8) {
    cvt_stride(W1, w1b, E_ * H_ * C_ / 4, blockIdx.x - N_ / 8, 1024);
    return;
  }
  const int tid = threadIdx.x;
  const int sub = tid & 31;
  const int n = blockIdx.x * 8 + (tid >> 5);
  const float4* xr = reinterpret_cast<const float4*>(x + (size_t)n * C_);
  ushort4* xw = reinterpret_cast<ushort4*>(xb + (size_t)n * C_);
  const float4* w0p = reinterpret_cast<const float4*>(Wr + 0 * C_);
  const float4* w1p = reinterpret_cast<const float4*>(Wr + 1 * C_);
  const float4* w2p = reinterpret_cast<const float4*>(Wr + 2 * C_);
  float s0 = 0.f, s1 = 0.f, s2 = 0.f;
#pragma unroll
  for (int j = 0; j < 7; ++j) {
    const int idx = sub + 32 * j;
    float4 v = xr[idx];
    ushort4 o;
    o.x = f2b(v.x); o.y = f2b(v.y); o.z = f2b(v.z); o.w = f2b(v.w);
    xw[idx] = o;
    float4 a = w0p[idx], b = w1p[idx], c = w2p[idx];
    s0 += v.x * a.x + v.y * a.y + v.z * a.z + v.w * a.w;
    s1 += v.x * b.x + v.y * b.y + v.z * b.z + v.w * b.w;
    s2 += v.x * c.x + v.y * c.y + v.z * c.z + v.w * c.w;
  }
#pragma unroll
  for (int off = 16; off > 0; off >>= 1) {
    s0 += __shfl_xor(s0, off);
    s1 += __shfl_xor(s1, off);
    s2 += __shfl_xor(s2, off);
  }
  if (sub == 0) {
    float m = fmaxf(s0, fmaxf(s1, s2));
    float e0 = expf(s0 - m), e1 = expf(s1 - m), e2 = expf(s2 - m);
    float sum = e0 + e1 + e2;
    float p0 = e0 / sum, p1 = e1 / sum, p2 = e2 / sum;
    int am = 0; float best = s0;
    if (s1 > best) { best = s1; am = 1; }
    if (s2 > best) { best = s2; am = 2; }
    float pa = (am == 0) ? p0 : ((am == 1) ? p1 : p2);
    eid[n] = am;
    gate[n] = pa / (pa + 1e-6f);
    pbuf[n * 3 + 0] = p0; pbuf[n * 3 + 1] = p1; pbuf[n * 3 + 2] = p2;
    float lse = m + logf(sum);
    lse2[n] = lse * lse;
  }
}

// ---- scatter: block-aggregated ----
__global__ __launch_bounds__(1024) void scatter_kernel(const int* __restrict__ eid,
                                                       int* __restrict__ counts,
                                                       int* __restrict__ perm) {
  __shared__ int hist[E_];
  __shared__ int base[E_];
  const int t = threadIdx.x;
  const int n = blockIdx.x * 1024 + t;
  if (t < E_) hist[t] = 0;
  __syncthreads();
  int e = eid[n];
  int l = atomicAdd(&hist[e], 1);
  __syncthreads();
  if (t < E_) base[t] = atomicAdd(&counts[t], hist[t]);
  __syncthreads();
  perm[e * N_ + base[e] + l] = n;
}

// ---- 256x128 tile, 8 waves (4M x 2N), single-buffer 48KB, T2 swizzle (R16-proven) ----
#define STAGE_TILE()                                                                    \
  do {                                                                                  \
    _Pragma("unroll")                                                                   \
    for (int i_ = 0; i_ < 4; ++i_) {                                                    \
      __builtin_amdgcn_global_load_lds(                                                 \
          (const __attribute__((address_space(1))) void*)pA_[i_],                       \
          (__attribute__((address_space(3))) void*)&shA[(wv * 4 + i_) * 512], 16, 0, 0); \
    }                                                                                   \
    _Pragma("unroll")                                                                   \
    for (int i_ = 0; i_ < 2; ++i_) {                                                    \
      __builtin_amdgcn_global_load_lds(                                                 \
          (const __attribute__((address_space(1))) void*)pB_[i_],                       \
          (__attribute__((address_space(3))) void*)&shB[(wv * 2 + i_) * 512], 16, 0, 0); \
    }                                                                                   \
    _Pragma("unroll")                                                                   \
    for (int i_ = 0; i_ < 4; ++i_) { pA_[i_] += 64; }                                   \
    _Pragma("unroll")                                                                   \
    for (int i_ = 0; i_ < 2; ++i_) { pB_[i_] += 64; }                                   \
  } while (0)

#define COMPUTE_TILE()                                                                  \
  do {                                                                                  \
    _Pragma("unroll")                                                                   \
    for (int kk = 0; kk < 2; ++kk) {                                                    \
      const int sl_ = ((kk * 4 + (lane >> 4)) ^ (lane & 7)) * 8;                        \
      short8 af[4], bfv[4];                                                             \
      _Pragma("unroll")                                                                 \
      for (int m = 0; m < 4; ++m) {                                                     \
        int row = wm * 64 + m * 16 + (lane & 15);                                       \
        af[m] = *reinterpret_cast<const short8*>(&shA[row * 64 + sl_]);                 \
      }                                                                                 \
      _Pragma("unroll")                                                                 \
      for (int nn = 0; nn < 4; ++nn) {                                                  \
        int row = wn * 64 + nn * 16 + (lane & 15);                                      \
        bfv[nn] = *reinterpret_cast<const short8*>(&shB[row * 64 + sl_]);               \
      }                                                                                 \
      _Pragma("unroll")                                                                 \
      for (int m = 0; m < 4; ++m)                                                       \
        _Pragma("unroll")                                                               \
        for (int nn = 0; nn < 4; ++nn)                                                  \
          acc[m][nn] = __builtin_amdgcn_mfma_f32_16x16x32_bf16(af[m], bfv[nn], acc[m][nn], 0, 0, 0); \
    }                                                                                   \
  } while (0)

#define K_LOOP(NT)                                                                      \
  do {                                                                                  \
    for (int kt = 0; kt < (NT); ++kt) {                                                 \
      STAGE_TILE();                                                                     \
      __syncthreads();                                                                  \
      COMPUTE_TILE();                                                                   \
      __syncthreads();                                                                  \
    }                                                                                   \
  } while (0)

// ---- GEMM1 (+fused W2 convert): R16-exact, h written in COMPACT slot order.
//      Compact base_e = prefix(counts): e0->0, e1->c0, e2->c0+c1 (total = N rows, fits OFF_HB).
__global__ __launch_bounds__(512) void gemm1_kernel(
    const unsigned short* __restrict__ xb,
    const unsigned short* __restrict__ w1b,
    unsigned short* __restrict__ h,
    const int* __restrict__ perm, const int* __restrict__ counts,
    const float* __restrict__ W2, unsigned short* __restrict__ w2b) {
  if (blockIdx.x < CVB) {
    cvt_stride(W2, w2b, E_ * C_ * H_ / 4, blockIdx.x, CVB);
    return;
  }
  const int c0 = counts[0], c1 = counts[1], c2 = counts[2];
  const int rt0 = (c0 + 255) >> 8, rt1 = (c1 + 255) >> 8, rt2 = (c2 + 255) >> 8;
  const int n0 = rt0 * 28, n1 = rt1 * 28, n2 = rt2 * 28;
  const int total = n0 + n1 + n2;
  const int lin = blockIdx.x - CVB;
  if (lin >= total) return;
  const int wgid = xcd_chunk(lin, total);
  int e, rem, rt_e, count, hbase;
  if (wgid < n0)            { e = 0; rem = wgid;           rt_e = rt0; count = c0; hbase = 0; }
  else if (wgid < n0 + n1)  { e = 1; rem = wgid - n0;      rt_e = rt1; count = c1; hbase = c0; }
  else                      { e = 2; rem = wgid - n0 - n1; rt_e = rt2; count = c2; hbase = c0 + c1; }
  int rowt, colt;
  grp_decode(rem, rt_e, 28, 4, 7, &rowt, &colt);
  const int row0 = rowt * 256;
  const int col0 = colt * 128;
  const int tid = threadIdx.x, lane = tid & 63, wv = tid >> 6;
  const int wm = wv >> 1, wn = wv & 1;
  const int* permE = perm + e * N_;
  const unsigned short* w1e = w1b + (size_t)e * H_ * C_;
  unsigned short* hE = h + (size_t)hbase * H_;

  __shared__ __align__(16) unsigned short shA[256 * 64];
  __shared__ __align__(16) unsigned short shB[128 * 64];

  f32x4 acc[4][4];
#pragma unroll
  for (int i = 0; i < 4; ++i)
#pragma unroll
    for (int j = 0; j < 4; ++j) acc[i][j] = (f32x4){0.f, 0.f, 0.f, 0.f};

  const int cc = (((lane & 7) ^ (lane >> 3))) * 8;
  const unsigned short* pA_[4];
  const unsigned short* pB_[2];
#pragma unroll
  for (int i = 0; i < 4; ++i) {
    int s = row0 + wv * 32 + i * 8 + (lane >> 3);
    if (s >= count) s = count - 1;
    pA_[i] = xb + (size_t)permE[s] * C_ + cc;
  }
#pragma unroll
  for (int i = 0; i < 2; ++i) {
    int r = wv * 16 + i * 8 + (lane >> 3);
    pB_[i] = w1e + (size_t)(col0 + r) * C_ + cc;
  }

  K_LOOP(C_ / 64);   // 14 K-steps

  // epilogue: write h by COMPACT slot (sequential rows, no token scatter)
#pragma unroll
  for (int m = 0; m < 4; ++m) {
    int rbase = wm * 64 + m * 16 + (lane >> 4) * 4;
#pragma unroll
    for (int i = 0; i < 4; ++i) {
      int s = row0 + rbase + i;
      if (s < count) {
#pragma unroll
        for (int nn = 0; nn < 4; ++nn) {
          int col = col0 + wn * 64 + nn * 16 + (lane & 15);
          hE[(size_t)s * H_ + col] = f2b(gelu_fast(acc[m][nn][i]));
        }
      }
    }
  }
}

// ---- GEMM2: R16 structure; A reads COMPACT h rows (contiguous; perm only for output) ----
__global__ __launch_bounds__(512) void gemm2_kernel(
    const unsigned short* __restrict__ h,
    const unsigned short* __restrict__ w2b,
    const float* __restrict__ x,
    const float* __restrict__ gate,
    float* __restrict__ out, float* __restrict__ P,
    const int* __restrict__ perm, const int* __restrict__ counts) {
  const int c0 = counts[0], c1 = counts[1], c2 = counts[2];
  const int rt0 = (c0 + 255) >> 8, rt1 = (c1 + 255) >> 8, rt2 = (c2 + 255) >> 8;
  const int n0 = rt0 * 14, n1 = rt1 * 14, n2 = rt2 * 14;
  const int total = n0 + n1 + n2;
  const int lin = blockIdx.x;
  if (lin >= total) return;
  const int wgid = xcd_chunk(lin, total);
  int e, rem, rt_e, count, hbase;
  if (wgid < n0)            { e = 0; rem = wgid;           rt_e = rt0; count = c0; hbase = 0; }
  else if (wgid < n0 + n1)  { e = 1; rem = wgid - n0;      rt_e = rt1; count = c1; hbase = c0; }
  else                      { e = 2; rem = wgid - n0 - n1; rt_e = rt2; count = c2; hbase = c0 + c1; }
  int rowt, c14;
  grp_decode(rem, rt_e, 14, 2, 7, &rowt, &c14);
  const int ks = c14 / 7;
  const int colt = c14 % 7;
  const int row0 = rowt * 256;
  const int col0 = colt * 128;
  const int kbase = ks * (H_ / 2);
  const int tid = threadIdx.x, lane = tid & 63, wv = tid >> 6;
  const int wm = wv >> 1, wn = wv & 1;
  const int* permE = perm + e * N_;
  const unsigned short* w2e = w2b + (size_t)e * C_ * H_;
  const unsigned short* hE = h + (size_t)hbase * H_;

  __shared__ __align__(16) unsigned short shA[256 * 64];
  __shared__ __align__(16) unsigned short shB[128 * 64];

  f32x4 acc[4][4];
#pragma unroll
  for (int i = 0; i < 4; ++i)
#pragma unroll
    for (int j = 0; j < 4; ++j) acc[i][j] = (f32x4){0.f, 0.f, 0.f, 0.f};

  const int cc = (((lane & 7) ^ (lane >> 3))) * 8;
  const unsigned short* pA_[4];
  const unsigned short* pB_[2];
#pragma unroll
  for (int i = 0; i < 4; ++i) {
    int s = row0 + wv * 32 + i * 8 + (lane >> 3);
    if (s >= count) s = count - 1;
    pA_[i] = hE + (size_t)s * H_ + kbase + cc;   // contiguous compact rows
  }
#pragma unroll
  for (int i = 0; i < 2; ++i) {
    int r = wv * 16 + i * 8 + (lane >> 3);
    pB_[i] = w2e + (size_t)(col0 + r) * H_ + kbase + cc;
  }

  for (int kt = 0; kt < (H_ / 2) / 64; ++kt) {   // 28 K-steps
    STAGE_TILE();
    __syncthreads();
    COMPUTE_TILE();
    __syncthreads();
  }

#pragma unroll
  for (int m = 0; m < 4; ++m) {
    int rbase = wm * 64 + m * 16 + (lane >> 4) * 4;
#pragma unroll
    for (int i = 0; i < 4; ++i) {
      int s = row0 + rbase + i;
      if (s < count) {
        int ntok = permE[s];
        float g = gate[ntok];
        if (ks == 0) {
#pragma unroll
          for (int nn = 0; nn < 4; ++nn) {
            int col = col0 + wn * 64 + nn * 16 + (lane & 15);
            out[(size_t)ntok * C_ + col] = x[(size_t)ntok * C_ + col] + g * acc[m][nn][i];
          }
        } else {
#pragma unroll
          for (int nn = 0; nn < 4; ++nn) {
            int col = col0 + wn * 64 + nn * 16 + (lane & 15);
            P[(size_t)ntok * C_ + col] = g * acc[m][nn][i];
          }
        }
      }
    }
  }
}

// ---- combine: out += P; block 0 additionally computes the losses ----
__global__ __launch_bounds__(256) void combine_kernel(
    float* __restrict__ out, const float* __restrict__ P, int n4,
    const float* __restrict__ lse2, const float* __restrict__ pbuf,
    const int* __restrict__ eid) {
  int stride = gridDim.x * blockDim.x;
  for (int i = blockIdx.x * blockDim.x + threadIdx.x; i < n4; i += stride) {
    float4 a = reinterpret_cast<float4*>(out)[i];
    float4 b = reinterpret_cast<const float4*>(P)[i];
    a.x += b.x; a.y += b.y; a.z += b.z; a.w += b.w;
    reinterpret_cast<float4*>(out)[i] = a;
  }
  if (blockIdx.x == 0) {
    __shared__ float sh[7][256];
    float a = 0.f, p0 = 0.f, p1 = 0.f, p2 = 0.f, c0 = 0.f, c1 = 0.f, c2 = 0.f;
    for (int n = threadIdx.x; n < N_; n += 256) {
      a += lse2[n];
      p0 += pbuf[n * 3 + 0]; p1 += pbuf[n * 3 + 1]; p2 += pbuf[n * 3 + 2];
      int e = eid[n];
      c0 += (e == 0); c1 += (e == 1); c2 += (e == 2);
    }
    sh[0][threadIdx.x] = a;
    sh[1][threadIdx.x] = p0; sh[2][threadIdx.x] = p1; sh[3][threadIdx.x] = p2;
    sh[4][threadIdx.x] = c0; sh[5][threadIdx.x] = c1; sh[6][threadIdx.x] = c2;
    for (int s = 128; s > 0; s >>= 1) {
      __syncthreads();
      if (threadIdx.x < (unsigned)s)
#pragma unroll
        for (int q = 0; q < 7; ++q) sh[q][threadIdx.x] += sh[q][threadIdx.x + s];
    }
    if (threadIdx.x == 0) {
      const float invN = 1.0f / (float)N_;
      float z = 0.001f * (sh[0][0] * invN);
      float aux = 0.1f * (float)E_ *
                  (sh[4][0] * invN * sh[1][0] * invN +
                   sh[5][0] * invN * sh[2][0] * invN +
                   sh[6][0] * invN * sh[3][0] * invN);
      out[(size_t)N_ * C_] = z + aux;
    }
  }
}

extern "C" void kernel_launch(void* const* d_in, const int* in_sizes, int n_in,
                              void* d_out, int out_size, void* d_ws, size_t ws_size,
                              hipStream_t stream) {
  const float* x  = (const float*)d_in[0];
  const float* Wr = (const float*)d_in[1];
  const float* W1 = (const float*)d_in[2];
  const float* W2 = (const float*)d_in[3];
  float* out = (float*)d_out;
  char* ws = (char*)d_ws;

  unsigned short* xb  = (unsigned short*)(ws + OFF_XB);
  unsigned short* w1b = (unsigned short*)(ws + OFF_W1B);
  unsigned short* w2b = (unsigned short*)(ws + OFF_W2B);
  unsigned short* hb  = (unsigned short*)(ws + OFF_HB);
  int*   perm  = (int*)(ws + OFF_PERM);
  int*   eid   = (int*)(ws + OFF_EID);
  float* gate  = (float*)(ws + OFF_GATE);
  float* pbuf  = (float*)(ws + OFF_PBUF);
  float* lse2  = (float*)(ws + OFF_LSE2);
  int*   counts = (int*)(ws + OFF_CNT);
  float* P     = (float*)(ws + OFF_P);

  hipMemsetAsync(counts, 0, E_ * sizeof(int), stream);

  // router blocks [0,1024) + W1-convert blocks [1024,2048)
  router_kernel<<<2048, 256, 0, stream>>>(x, Wr, xb, eid, gate, pbuf, lse2, W1, w1b);
  scatter_kernel<<<N_ / 1024, 1024, 0, stream>>>(eid, counts, perm);

  // W2-convert blocks [0,CVB) + gemm1 blocks [CVB, CVB + 14*28*3)
  gemm1_kernel<<<CVB + NRT * 28 * E_, 512, 0, stream>>>(xb, w1b, hb, perm, counts, W2, w2b);
  gemm2_kernel<<<NRT * 14 * E_, 512, 0, stream>>>(hb, w2b, x, gate, out, P, perm, counts);
  combine_kernel<<<2048, 256, 0, stream>>>(out, P, N_ * C_ / 4, lse2, pbuf, eid);
}